// Round 1
// baseline (1379.737 us; speedup 1.0000x reference)
//
#include <hip/hip_runtime.h>

// LIF benchmark: xs = einsum('tbf,gf->tbg', S, W)  (fp32 GEMM, A=S [T*B,512], B=W [512,512], NT)
// then sequential scan over T with per-neuron (v,i) state and heaviside threshold.
// Outputs: [z_final, z_final, v_final, i_final], each [128,512] fp32.

#define T_DIM 1024
#define B_DIM 128
#define F_DIM 512
#define NB (B_DIM * F_DIM)  // 65536 neurons

// ---------------- GEMM: C[m][n] = sum_k A[m][k] * W[n][k] ----------------
// Tile 128x128, 256 threads, 8x8 micro-tile, KC=32.
#define TM 128
#define TN 128
#define KC 32
#define LDSS 132  // padded leading dim (floats): 132%32=4 -> banks rotate per k; float4-aligned

__global__ __launch_bounds__(256, 2)
void gemm_kernel(const float* __restrict__ A, const float* __restrict__ W,
                 float* __restrict__ C) {
    __shared__ float As[KC * LDSS];  // [k][m]
    __shared__ float Bs[KC * LDSS];  // [k][n]
    const int tid = threadIdx.x;
    const int m0 = blockIdx.x * TM;
    const int n0 = blockIdx.y * TN;
    // n fast-varying across lanes => coalesced C stores
    const int tn = (tid & 15) * 4;   // + {0..3} and +64
    const int tm = (tid >> 4) * 4;
    const int srow = tid >> 3;       // staging row 0..31 (+32p)
    const int sk = (tid & 7) * 4;    // staging k 0,4,...,28

    float acc[8][8];
    #pragma unroll
    for (int i = 0; i < 8; ++i)
        #pragma unroll
        for (int j = 0; j < 8; ++j) acc[i][j] = 0.f;

    for (int k0 = 0; k0 < F_DIM; k0 += KC) {
        // stage A,B tiles transposed into LDS ([k][row])
        #pragma unroll
        for (int p = 0; p < 4; ++p) {
            const int r = srow + 32 * p;
            const float4 av = *(const float4*)(A + (size_t)(m0 + r) * F_DIM + k0 + sk);
            As[(sk + 0) * LDSS + r] = av.x;
            As[(sk + 1) * LDSS + r] = av.y;
            As[(sk + 2) * LDSS + r] = av.z;
            As[(sk + 3) * LDSS + r] = av.w;
            const float4 bv = *(const float4*)(W + (size_t)(n0 + r) * F_DIM + k0 + sk);
            Bs[(sk + 0) * LDSS + r] = bv.x;
            Bs[(sk + 1) * LDSS + r] = bv.y;
            Bs[(sk + 2) * LDSS + r] = bv.z;
            Bs[(sk + 3) * LDSS + r] = bv.w;
        }
        __syncthreads();
        #pragma unroll 8
        for (int k = 0; k < KC; ++k) {
            const float4 a0 = *(const float4*)(As + k * LDSS + tm);
            const float4 a1 = *(const float4*)(As + k * LDSS + tm + 64);
            const float4 b0 = *(const float4*)(Bs + k * LDSS + tn);
            const float4 b1 = *(const float4*)(Bs + k * LDSS + tn + 64);
            const float a[8] = {a0.x, a0.y, a0.z, a0.w, a1.x, a1.y, a1.z, a1.w};
            const float b[8] = {b0.x, b0.y, b0.z, b0.w, b1.x, b1.y, b1.z, b1.w};
            #pragma unroll
            for (int i = 0; i < 8; ++i)
                #pragma unroll
                for (int j = 0; j < 8; ++j)
                    acc[i][j] += a[i] * b[j];
        }
        __syncthreads();
    }
    #pragma unroll
    for (int i = 0; i < 8; ++i) {
        const int m = m0 + ((i < 4) ? (tm + i) : (tm + 60 + i));  // tm+64+(i-4)
        const float4 c0 = make_float4(acc[i][0], acc[i][1], acc[i][2], acc[i][3]);
        const float4 c1 = make_float4(acc[i][4], acc[i][5], acc[i][6], acc[i][7]);
        *(float4*)(C + (size_t)m * F_DIM + n0 + tn) = c0;
        *(float4*)(C + (size_t)m * F_DIM + n0 + tn + 64) = c1;
    }
}

// ---------------- sequential LIF scan over a chunk of Tc steps ----------------
// Explicit _rn intrinsics: forbid fma contraction so rounding matches the
// reference's separate mul+add (matters at the spike threshold).
__global__ __launch_bounds__(256)
void scan_kernel(const float* __restrict__ xs, float* __restrict__ vi,
                 float* __restrict__ out, int Tc, int first, int last) {
    const int j = blockIdx.x * 256 + threadIdx.x;  // neuron id, 0..NB-1
    float v, cur;
    if (first) { v = 0.f; cur = 0.f; }
    else       { v = vi[j]; cur = vi[NB + j]; }
    float z = 0.f;
    for (int t = 0; t < Tc; ++t) {
        const float x = xs[(size_t)t * NB + j];
        // v_decayed = v + 0.1f*((0-v)+i) ; i_decayed = i + (-0.2f)*i
        const float vd = __fadd_rn(v, __fmul_rn(0.1f, __fsub_rn(cur, v)));
        const float id = __fadd_rn(cur, __fmul_rn(-0.2f, cur));
        const bool sp = vd > 1.0f;  // == (vd - 1.0f) > 0 in fp32 (Sterbenz)
        z = sp ? 1.f : 0.f;
        v = sp ? 0.f : vd;
        cur = __fadd_rn(id, x);
    }
    if (last) {
        out[j]           = z;
        out[NB + j]      = z;
        out[2 * NB + j]  = v;
        out[3 * NB + j]  = cur;
    } else {
        vi[j]      = v;
        vi[NB + j] = cur;
    }
}

extern "C" void kernel_launch(void* const* d_in, const int* in_sizes, int n_in,
                              void* d_out, int out_size, void* d_ws, size_t ws_size,
                              hipStream_t stream) {
    const float* S = (const float*)d_in[0];  // [T,B,F] fp32
    const float* W = (const float*)d_in[1];  // [F,F] fp32
    float* out = (float*)d_out;
    float* vi = (float*)d_ws;        // 2*NB floats of state
    float* xs = vi + 2 * NB;         // chunk buffer [Tc, NB]
    // pick largest power-of-two chunk Tc whose xs buffer fits the workspace
    const size_t avail_f = (ws_size / 4 > (size_t)(2 * NB)) ? ws_size / 4 - 2 * NB : 0;
    int Tc = T_DIM;
    while (Tc > 1 && (size_t)Tc * NB > avail_f) Tc >>= 1;
    const int nc = T_DIM / Tc;
    for (int c = 0; c < nc; ++c) {
        const int M = Tc * B_DIM;
        dim3 grid(M / TM, F_DIM / TN);
        gemm_kernel<<<grid, 256, 0, stream>>>(S + (size_t)c * Tc * NB, W, xs);
        scan_kernel<<<NB / 256, 256, 0, stream>>>(xs, vi, out, Tc,
                                                  (c == 0) ? 1 : 0,
                                                  (c == nc - 1) ? 1 : 0);
    }
}